// Round 1
// baseline (1316.886 us; speedup 1.0000x reference)
//
#include <hip/hip_runtime.h>

#define NN 50000
#define NE 320000
#define D 256

// ws layout (floats):
//   aggX [NN*D] | deg [NN] | WT [512*D] | bvec [D]
// WT[k][j]: k<256 -> w1[j][k]  (x term);  k>=256 -> Wc[j][k-256], Wc = w2@w3

__global__ __launch_bounds__(256) void prep_weights(
        const float* __restrict__ w1, const float* __restrict__ w2,
        const float* __restrict__ w3, const float* __restrict__ b3,
        float* __restrict__ WT, float* __restrict__ bvec) {
    __shared__ float s_col[D];
    const int j = threadIdx.x;   // output col (fast dim of WT)
    const int k = blockIdx.x;    // K row
    if (k < D) {
        WT[k * D + j] = w1[j * D + k];
        s_col[j] = w3[j * D + k];          // w3[o][k], o = j
        __syncthreads();
        float acc = 0.f;
        const float* w2r = w2 + j * D;
        #pragma unroll 8
        for (int o = 0; o < D; ++o) acc += w2r[o] * s_col[o];
        WT[(D + k) * D + j] = acc;         // Wc[j][k] = sum_o w2[j][o]*w3[o][k]
    } else {
        float acc = 0.f;
        const float* w2r = w2 + j * D;
        #pragma unroll 8
        for (int o = 0; o < D; ++o) acc += w2r[o] * b3[o];
        bvec[j] = acc;                     // (w2 @ b3)[j]
    }
}

__global__ __launch_bounds__(256) void scatter_agg(
        const float* __restrict__ x, const int* __restrict__ ei,
        float* __restrict__ aggX, float* __restrict__ deg) {
    const int e = blockIdx.x * 4 + (threadIdx.x >> 6);
    const int lane = threadIdx.x & 63;
    if (e >= NE) return;
    const int src = ei[e];        // sender
    const int dst = ei[NE + e];   // receiver
    const float4 v = *reinterpret_cast<const float4*>(x + (size_t)src * D + lane * 4);
    float* a = aggX + (size_t)dst * D + lane * 4;
    atomicAdd(a + 0, v.x);
    atomicAdd(a + 1, v.y);
    atomicAdd(a + 2, v.z);
    atomicAdd(a + 3, v.w);
    if (lane == 0) atomicAdd(deg + dst, 1.0f);
}

// out[n][j] = sum_k x[n][k]*WT[k][j] + sum_k aggX[n][k]*WT[256+k][j] + deg[n]*bvec[j]
__global__ __launch_bounds__(256) void fused_out(
        const float* __restrict__ x, const float* __restrict__ aggX,
        const float* __restrict__ WT, const float* __restrict__ bvec,
        const float* __restrict__ deg, float* __restrict__ out) {
    __shared__ float tile[64][64];   // 16 KB activation chunk
    const int tid = threadIdx.x;
    const int tc = tid & 31;         // 32 col-groups * 8 cols = 256
    const int tr = tid >> 5;         // 8 row-groups * 8 rows = 64
    const int row0 = blockIdx.x * 64;

    float acc[8][8];
    #pragma unroll
    for (int r = 0; r < 8; ++r)
        #pragma unroll
        for (int c = 0; c < 8; ++c) acc[r][c] = 0.f;

    #pragma unroll
    for (int s = 0; s < 2; ++s) {
        const float* __restrict__ srcp = s ? aggX : x;
        const float* __restrict__ wb = WT + (size_t)s * D * D;
        for (int kc = 0; kc < D; kc += 64) {
            __syncthreads();
            #pragma unroll
            for (int p = 0; p < 4; ++p) {
                int i = tid + p * 256;
                int r = i >> 4;
                int c4 = (i & 15) * 4;
                int gr = row0 + r;
                float4 v = make_float4(0.f, 0.f, 0.f, 0.f);
                if (gr < NN)
                    v = *reinterpret_cast<const float4*>(srcp + (size_t)gr * D + kc + c4);
                *reinterpret_cast<float4*>(&tile[r][c4]) = v;
            }
            __syncthreads();
            #pragma unroll 4
            for (int kk = 0; kk < 64; ++kk) {
                const float* wrow = wb + (size_t)(kc + kk) * D + tc * 8;
                float4 w0 = *reinterpret_cast<const float4*>(wrow);
                float4 w1v = *reinterpret_cast<const float4*>(wrow + 4);
                float wv[8] = {w0.x, w0.y, w0.z, w0.w, w1v.x, w1v.y, w1v.z, w1v.w};
                #pragma unroll
                for (int r = 0; r < 8; ++r) {
                    float a = tile[tr * 8 + r][kk];
                    #pragma unroll
                    for (int c = 0; c < 8; ++c) acc[r][c] += a * wv[c];
                }
            }
        }
    }

    float4 b0 = *reinterpret_cast<const float4*>(bvec + tc * 8);
    float4 b1 = *reinterpret_cast<const float4*>(bvec + tc * 8 + 4);
    float bv[8] = {b0.x, b0.y, b0.z, b0.w, b1.x, b1.y, b1.z, b1.w};
    #pragma unroll
    for (int r = 0; r < 8; ++r) {
        int row = row0 + tr * 8 + r;
        if (row >= NN) break;
        float dg = deg[row];
        float o[8];
        #pragma unroll
        for (int c = 0; c < 8; ++c) o[c] = acc[r][c] + dg * bv[c];
        float* op = out + (size_t)row * D + tc * 8;
        *reinterpret_cast<float4*>(op)     = make_float4(o[0], o[1], o[2], o[3]);
        *reinterpret_cast<float4*>(op + 4) = make_float4(o[4], o[5], o[6], o[7]);
    }
}

extern "C" void kernel_launch(void* const* d_in, const int* in_sizes, int n_in,
                              void* d_out, int out_size, void* d_ws, size_t ws_size,
                              hipStream_t stream) {
    const float* x  = (const float*)d_in[0];
    const int*   ei = (const int*)d_in[1];
    const float* w1 = (const float*)d_in[2];
    const float* w2 = (const float*)d_in[3];
    const float* w3 = (const float*)d_in[4];
    const float* b3 = (const float*)d_in[5];
    float* out = (float*)d_out;
    float* ws  = (float*)d_ws;

    float* aggX = ws;                          // NN*D floats
    float* deg  = ws + (size_t)NN * D;         // NN floats
    float* WT   = deg + NN;                    // 512*D floats (16B aligned)
    float* bvec = WT + 2 * D * D;              // D floats

    hipMemsetAsync(aggX, 0, ((size_t)NN * D + NN) * sizeof(float), stream);
    prep_weights<<<D + 1, 256, 0, stream>>>(w1, w2, w3, b3, WT, bvec);
    scatter_agg<<<NE / 4, 256, 0, stream>>>(x, ei, aggX, deg);
    fused_out<<<(NN + 63) / 64, 256, 0, stream>>>(x, aggX, WT, bvec, deg, out);
}

// Round 2
// 301.002 us; speedup vs baseline: 4.3750x; 4.3750x over previous
//
#include <hip/hip_runtime.h>

#define NN 50000
#define NE 320000
#define D 256
#define CAP 64   // per-node in-edge bucket capacity; deg ~ Poisson(6.4), max << 64

// ws layout:
//   aggX [NN*D] f32 | WT [512*D] f32 | bvec [D] f32 | cnt [NN] i32 | csr [NN*CAP] i32

__global__ __launch_bounds__(256) void prep_weights(
        const float* __restrict__ w1, const float* __restrict__ w2,
        const float* __restrict__ w3, const float* __restrict__ b3,
        float* __restrict__ WT, float* __restrict__ bvec) {
    __shared__ float s_col[D];
    const int j = threadIdx.x;   // output col (fast dim of WT)
    const int k = blockIdx.x;    // K row
    if (k < D) {
        WT[k * D + j] = w1[j * D + k];
        s_col[j] = w3[j * D + k];          // w3[o][k], o = j
        __syncthreads();
        float acc = 0.f;
        const float* w2r = w2 + j * D;
        #pragma unroll 8
        for (int o = 0; o < D; ++o) acc += w2r[o] * s_col[o];
        WT[(D + k) * D + j] = acc;         // Wc[j][k] = sum_o w2[j][o]*w3[o][k]
    } else {
        float acc = 0.f;
        const float* w2r = w2 + j * D;
        #pragma unroll 8
        for (int o = 0; o < D; ++o) acc += w2r[o] * b3[o];
        bvec[j] = acc;                     // (w2 @ b3)[j]
    }
}

__global__ __launch_bounds__(256) void fill_csr(
        const int* __restrict__ ei, int* __restrict__ csr, int* __restrict__ cnt) {
    const int e = blockIdx.x * 256 + threadIdx.x;
    if (e >= NE) return;
    const int src = ei[e];        // sender
    const int dst = ei[NE + e];   // receiver
    const int pos = atomicAdd(cnt + dst, 1);
    if (pos < CAP) csr[(size_t)dst * CAP + pos] = src;
}

// one wave per node: aggX[n] = sum over in-edges of x[src]
__global__ __launch_bounds__(256) void agg_gather(
        const float* __restrict__ x, const int* __restrict__ csr,
        const int* __restrict__ cnt, float* __restrict__ aggX) {
    const int node = blockIdx.x * 4 + (threadIdx.x >> 6);
    const int lane = threadIdx.x & 63;
    if (node >= NN) return;
    int d = cnt[node];
    if (d > CAP) d = CAP;
    const int* __restrict__ row = csr + (size_t)node * CAP;
    float4 acc = make_float4(0.f, 0.f, 0.f, 0.f);
    int i = 0;
    for (; i + 2 <= d; i += 2) {          // 2-deep to overlap gather latency
        const int s0 = row[i], s1 = row[i + 1];
        const float4 v0 = *reinterpret_cast<const float4*>(x + (size_t)s0 * D + lane * 4);
        const float4 v1 = *reinterpret_cast<const float4*>(x + (size_t)s1 * D + lane * 4);
        acc.x += v0.x + v1.x; acc.y += v0.y + v1.y;
        acc.z += v0.z + v1.z; acc.w += v0.w + v1.w;
    }
    if (i < d) {
        const float4 v = *reinterpret_cast<const float4*>(x + (size_t)row[i] * D + lane * 4);
        acc.x += v.x; acc.y += v.y; acc.z += v.z; acc.w += v.w;
    }
    *reinterpret_cast<float4*>(aggX + (size_t)node * D + lane * 4) = acc;
}

// out[n][j] = sum_k x[n][k]*WT[k][j] + sum_k aggX[n][k]*WT[256+k][j] + deg[n]*bvec[j]
__global__ __launch_bounds__(256) void fused_out(
        const float* __restrict__ x, const float* __restrict__ aggX,
        const float* __restrict__ WT, const float* __restrict__ bvec,
        const int* __restrict__ cnt, float* __restrict__ out) {
    __shared__ float tile[64][64];   // 16 KB activation chunk
    const int tid = threadIdx.x;
    const int tc = tid & 31;         // 32 col-groups * 8 cols = 256
    const int tr = tid >> 5;         // 8 row-groups * 8 rows = 64
    const int row0 = blockIdx.x * 64;

    float acc[8][8];
    #pragma unroll
    for (int r = 0; r < 8; ++r)
        #pragma unroll
        for (int c = 0; c < 8; ++c) acc[r][c] = 0.f;

    #pragma unroll
    for (int s = 0; s < 2; ++s) {
        const float* __restrict__ srcp = s ? aggX : x;
        const float* __restrict__ wb = WT + (size_t)s * D * D;
        for (int kc = 0; kc < D; kc += 64) {
            __syncthreads();
            #pragma unroll
            for (int p = 0; p < 4; ++p) {
                int i = tid + p * 256;
                int r = i >> 4;
                int c4 = (i & 15) * 4;
                int gr = row0 + r;
                float4 v = make_float4(0.f, 0.f, 0.f, 0.f);
                if (gr < NN)
                    v = *reinterpret_cast<const float4*>(srcp + (size_t)gr * D + kc + c4);
                *reinterpret_cast<float4*>(&tile[r][c4]) = v;
            }
            __syncthreads();
            #pragma unroll 4
            for (int kk = 0; kk < 64; ++kk) {
                const float* wrow = wb + (size_t)(kc + kk) * D + tc * 8;
                float4 w0 = *reinterpret_cast<const float4*>(wrow);
                float4 w1v = *reinterpret_cast<const float4*>(wrow + 4);
                float wv[8] = {w0.x, w0.y, w0.z, w0.w, w1v.x, w1v.y, w1v.z, w1v.w};
                #pragma unroll
                for (int r = 0; r < 8; ++r) {
                    float a = tile[tr * 8 + r][kk];
                    #pragma unroll
                    for (int c = 0; c < 8; ++c) acc[r][c] += a * wv[c];
                }
            }
        }
    }

    float4 b0 = *reinterpret_cast<const float4*>(bvec + tc * 8);
    float4 b1 = *reinterpret_cast<const float4*>(bvec + tc * 8 + 4);
    float bv[8] = {b0.x, b0.y, b0.z, b0.w, b1.x, b1.y, b1.z, b1.w};
    #pragma unroll
    for (int r = 0; r < 8; ++r) {
        int row = row0 + tr * 8 + r;
        if (row >= NN) break;
        float dg = (float)cnt[row];
        float o[8];
        #pragma unroll
        for (int c = 0; c < 8; ++c) o[c] = acc[r][c] + dg * bv[c];
        float* op = out + (size_t)row * D + tc * 8;
        *reinterpret_cast<float4*>(op)     = make_float4(o[0], o[1], o[2], o[3]);
        *reinterpret_cast<float4*>(op + 4) = make_float4(o[4], o[5], o[6], o[7]);
    }
}

extern "C" void kernel_launch(void* const* d_in, const int* in_sizes, int n_in,
                              void* d_out, int out_size, void* d_ws, size_t ws_size,
                              hipStream_t stream) {
    const float* x  = (const float*)d_in[0];
    const int*   ei = (const int*)d_in[1];
    const float* w1 = (const float*)d_in[2];
    const float* w2 = (const float*)d_in[3];
    const float* w3 = (const float*)d_in[4];
    const float* b3 = (const float*)d_in[5];
    float* out = (float*)d_out;
    float* ws  = (float*)d_ws;

    float* aggX = ws;                          // NN*D floats
    float* WT   = aggX + (size_t)NN * D;       // 512*D floats
    float* bvec = WT + 2 * D * D;              // D floats
    int*   cnt  = (int*)(bvec + D);            // NN ints
    int*   csr  = cnt + NN;                    // NN*CAP ints

    hipMemsetAsync(cnt, 0, NN * sizeof(int), stream);
    prep_weights<<<D + 1, 256, 0, stream>>>(w1, w2, w3, b3, WT, bvec);
    fill_csr<<<(NE + 255) / 256, 256, 0, stream>>>(ei, csr, cnt);
    agg_gather<<<(NN + 3) / 4, 256, 0, stream>>>(x, csr, cnt, aggX);
    fused_out<<<(NN + 63) / 64, 256, 0, stream>>>(x, aggX, WT, bvec, cnt, out);
}

// Round 3
// 113.293 us; speedup vs baseline: 11.6237x; 2.6568x over previous
//
#include <hip/hip_runtime.h>

#define NN 50000
#define NPAD 50048   // 391*128 = 50048, pad so GEMM staging stays in-bounds
#define NE 320000
#define D 256
#define CAP 64       // per-node in-edge capacity; deg ~ Poisson(6.4)

typedef __bf16 bf16x8 __attribute__((ext_vector_type(8)));
typedef float f32x4 __attribute__((ext_vector_type(4)));

__device__ __forceinline__ unsigned short f2bf(float f) {
    unsigned u = __builtin_bit_cast(unsigned, f);
    unsigned r = u + 0x7FFFu + ((u >> 16) & 1u);   // RNE
    return (unsigned short)(r >> 16);
}
__device__ __forceinline__ float bf2f(unsigned short h) {
    return __builtin_bit_cast(float, (unsigned)h << 16);
}

// WTT[j][k] (bf16, row stride 512): k<256 -> w1[j][k]; k>=256 -> (w2@w3)[j][k-256]
// bvec[j] = (w2 @ b3)[j]  (f32)
__global__ __launch_bounds__(256) void prep_weights(
        const float* __restrict__ w1, const float* __restrict__ w2,
        const float* __restrict__ w3, const float* __restrict__ b3,
        unsigned short* __restrict__ WTT, float* __restrict__ bvec) {
    const int j = blockIdx.x;    // output row of WTT
    const int k = threadIdx.x;
    __shared__ float w2row[D];
    __shared__ float red[D];
    w2row[k] = w2[j * D + k];
    __syncthreads();
    float acc = 0.f;
    #pragma unroll 8
    for (int o = 0; o < D; ++o) acc += w2row[o] * w3[o * D + k];   // coalesced in k
    WTT[(size_t)j * 512 + k]       = f2bf(w1[j * D + k]);
    WTT[(size_t)j * 512 + D + k]   = f2bf(acc);
    red[k] = w2row[k] * b3[k];
    __syncthreads();
    for (int s = 128; s > 0; s >>= 1) {
        if (k < s) red[k] += red[k + s];
        __syncthreads();
    }
    if (k == 0) bvec[j] = red[0];
}

__global__ __launch_bounds__(256) void convert_x(
        const float* __restrict__ x, unsigned short* __restrict__ xbf) {
    const size_t i = ((size_t)blockIdx.x * 256 + threadIdx.x) * 8;
    if (i >= (size_t)NN * D) return;
    const float4 a = *reinterpret_cast<const float4*>(x + i);
    const float4 b = *reinterpret_cast<const float4*>(x + i + 4);
    ushort4 o0 = {f2bf(a.x), f2bf(a.y), f2bf(a.z), f2bf(a.w)};
    ushort4 o1 = {f2bf(b.x), f2bf(b.y), f2bf(b.z), f2bf(b.w)};
    *reinterpret_cast<ushort4*>(xbf + i)     = o0;
    *reinterpret_cast<ushort4*>(xbf + i + 4) = o1;
}

__global__ __launch_bounds__(256) void fill_csr(
        const int* __restrict__ ei, int* __restrict__ csr, int* __restrict__ cnt) {
    const int e = blockIdx.x * 256 + threadIdx.x;
    if (e >= NE) return;
    const int src = ei[e];
    const int dst = ei[NE + e];
    const int pos = atomicAdd(cnt + dst, 1);
    if (pos < CAP) csr[(size_t)dst * CAP + pos] = src;
}

// one wave per node: aggbf[n] = bf16( sum over in-edges of xbf[src] )
__global__ __launch_bounds__(256) void agg_gather(
        const unsigned short* __restrict__ xbf, const int* __restrict__ csr,
        const int* __restrict__ cnt, unsigned short* __restrict__ aggbf) {
    const int node = blockIdx.x * 4 + (threadIdx.x >> 6);
    const int lane = threadIdx.x & 63;
    if (node >= NN) return;
    int d = cnt[node]; if (d > CAP) d = CAP;
    const int* __restrict__ row = csr + (size_t)node * CAP;
    float a0 = 0.f, a1 = 0.f, a2 = 0.f, a3 = 0.f;
    int i = 0;
    for (; i + 2 <= d; i += 2) {
        const ushort4 v0 = *reinterpret_cast<const ushort4*>(xbf + (size_t)row[i] * D + lane * 4);
        const ushort4 v1 = *reinterpret_cast<const ushort4*>(xbf + (size_t)row[i + 1] * D + lane * 4);
        a0 += bf2f(v0.x) + bf2f(v1.x); a1 += bf2f(v0.y) + bf2f(v1.y);
        a2 += bf2f(v0.z) + bf2f(v1.z); a3 += bf2f(v0.w) + bf2f(v1.w);
    }
    if (i < d) {
        const ushort4 v = *reinterpret_cast<const ushort4*>(xbf + (size_t)row[i] * D + lane * 4);
        a0 += bf2f(v.x); a1 += bf2f(v.y); a2 += bf2f(v.z); a3 += bf2f(v.w);
    }
    ushort4 o = {f2bf(a0), f2bf(a1), f2bf(a2), f2bf(a3)};
    *reinterpret_cast<ushort4*>(aggbf + (size_t)node * D + lane * 4) = o;
}

// out[MxN] = [xbf | aggbf] (M x 512) @ WTT^T (512 x 256) + deg*bvec
// 128x128 tile, 4 waves (2x2), each wave 64x64 via 4x4 frags of 16x16x32 bf16.
__global__ __launch_bounds__(256) void gemm_mfma(
        const unsigned short* __restrict__ xbf, const unsigned short* __restrict__ aggbf,
        const unsigned short* __restrict__ WTT, const float* __restrict__ bvec,
        const int* __restrict__ cnt, float* __restrict__ out) {
    __shared__ __align__(16) unsigned short ldsA[128 * 64];  // [row][k-chunk swizzled]
    __shared__ __align__(16) unsigned short ldsB[128 * 64];  // [n][k-chunk swizzled]

    const int tid  = threadIdx.x;
    const int w    = tid >> 6;
    const int lane = tid & 63;
    const int wm   = w >> 1, wn = w & 1;
    const int mb   = blockIdx.x >> 1;
    const int nb0  = (blockIdx.x & 1) * 128;
    const int gr0  = mb * 128;

    f32x4 acc[4][4];
    #pragma unroll
    for (int a = 0; a < 4; ++a)
        #pragma unroll
        for (int b = 0; b < 4; ++b) acc[a][b] = (f32x4)0.f;

    for (int kt = 0; kt < 8; ++kt) {
        if (kt) __syncthreads();
        // ---- stage A: 128 rows x 64 k of activation (x for kt<4, agg else)
        {
            const unsigned short* __restrict__ src = (kt < 4) ? xbf : aggbf;
            const int kc = (kt & 3) * 64;
            #pragma unroll
            for (int p = 0; p < 4; ++p) {
                const int idx = p * 256 + w * 64 + lane;       // 16B unit id
                const int r = idx >> 3, c = idx & 7;
                const int gcol = kc + ((c ^ (r & 7)) << 3);    // pre-swizzled source
                const unsigned short* gp = src + ((size_t)(gr0 + r) << 8) + gcol;
                unsigned short* lp = &ldsA[(size_t)(p * 256 + w * 64) << 3]; // wave-uniform
                __builtin_amdgcn_global_load_lds(
                    (const __attribute__((address_space(1))) void*)(const void*)gp,
                    (__attribute__((address_space(3))) void*)(void*)lp, 16, 0, 0);
            }
        }
        // ---- stage B: 128 n-rows x 64 k of WTT (row stride 512)
        {
            const int kc = kt * 64;
            #pragma unroll
            for (int p = 0; p < 4; ++p) {
                const int idx = p * 256 + w * 64 + lane;
                const int r = idx >> 3, c = idx & 7;
                const int gcol = kc + ((c ^ (r & 7)) << 3);
                const unsigned short* gp = WTT + ((size_t)(nb0 + r) << 9) + gcol;
                unsigned short* lp = &ldsB[(size_t)(p * 256 + w * 64) << 3];
                __builtin_amdgcn_global_load_lds(
                    (const __attribute__((address_space(1))) void*)(const void*)gp,
                    (__attribute__((address_space(3))) void*)(void*)lp, 16, 0, 0);
            }
        }
        __syncthreads();   // compiler drains vmcnt before barrier

        #pragma unroll
        for (int kh = 0; kh < 2; ++kh) {
            const int cbase = kh * 4 + (lane >> 4);            // chunk 0..7
            bf16x8 af[4], bf[4];
            #pragma unroll
            for (int f = 0; f < 4; ++f) {
                const int ra = wm * 64 + f * 16 + (lane & 15);
                af[f] = *reinterpret_cast<const bf16x8*>(
                    &ldsA[ra * 64 + ((cbase ^ (ra & 7)) << 3)]);
                const int rb = wn * 64 + f * 16 + (lane & 15);
                bf[f] = *reinterpret_cast<const bf16x8*>(
                    &ldsB[rb * 64 + ((cbase ^ (rb & 7)) << 3)]);
            }
            #pragma unroll
            for (int fm = 0; fm < 4; ++fm)
                #pragma unroll
                for (int fn = 0; fn < 4; ++fn)
                    acc[fm][fn] = __builtin_amdgcn_mfma_f32_16x16x32_bf16(
                        af[fm], bf[fn], acc[fm][fn], 0, 0, 0);
        }
    }

    // ---- epilogue: out = acc + deg*bvec ; C/D layout col=lane&15, row=(lane>>4)*4+i
    const int col0 = nb0 + wn * 64 + (lane & 15);
    float bv[4];
    #pragma unroll
    for (int fn = 0; fn < 4; ++fn) bv[fn] = bvec[col0 + fn * 16];
    #pragma unroll
    for (int fm = 0; fm < 4; ++fm) {
        #pragma unroll
        for (int i = 0; i < 4; ++i) {
            const int row = gr0 + wm * 64 + fm * 16 + ((lane >> 4) << 2) + i;
            if (row < NN) {
                const float dg = (float)cnt[row];
                float* op = out + ((size_t)row << 8) + col0;
                #pragma unroll
                for (int fn = 0; fn < 4; ++fn)
                    op[fn * 16] = acc[fm][fn][i] + dg * bv[fn];
            }
        }
    }
}

extern "C" void kernel_launch(void* const* d_in, const int* in_sizes, int n_in,
                              void* d_out, int out_size, void* d_ws, size_t ws_size,
                              hipStream_t stream) {
    const float* x  = (const float*)d_in[0];
    const int*   ei = (const int*)d_in[1];
    const float* w1 = (const float*)d_in[2];
    const float* w2 = (const float*)d_in[3];
    const float* w3 = (const float*)d_in[4];
    const float* b3 = (const float*)d_in[5];
    float* out = (float*)d_out;

    unsigned short* xbf   = (unsigned short*)d_ws;               // NPAD*256
    unsigned short* aggbf = xbf + (size_t)NPAD * D;              // NPAD*256
    unsigned short* WTT   = aggbf + (size_t)NPAD * D;            // 256*512
    float* bvec = (float*)(WTT + (size_t)D * 512);               // 256
    int*   cnt  = (int*)(bvec + D);                              // NN
    int*   csr  = cnt + NN;                                      // NN*CAP

    hipMemsetAsync(cnt, 0, NN * sizeof(int), stream);
    prep_weights<<<D, 256, 0, stream>>>(w1, w2, w3, b3, WTT, bvec);
    convert_x<<<(NN * D) / (256 * 8), 256, 0, stream>>>(x, xbf);
    fill_csr<<<(NE + 255) / 256, 256, 0, stream>>>(ei, csr, cnt);
    agg_gather<<<(NN + 3) / 4, 256, 0, stream>>>(xbf, csr, cnt, aggbf);
    gemm_mfma<<<((NN + 127) / 128) * 2, 256, 0, stream>>>(xbf, aggbf, WTT, bvec, cnt, out);
}

// Round 4
// 111.960 us; speedup vs baseline: 11.7621x; 1.0119x over previous
//
#include <hip/hip_runtime.h>

#define NN 50000
#define NPAD 50048   // 391*128, pad so GEMM staging stays in-bounds
#define NE 320000
#define D 256
#define CAP 64       // per-node in-edge capacity; deg ~ Poisson(6.4)

typedef __bf16 bf16x8 __attribute__((ext_vector_type(8)));
typedef float f32x4 __attribute__((ext_vector_type(4)));

__device__ __forceinline__ unsigned short f2bf(float f) {
    unsigned u = __builtin_bit_cast(unsigned, f);
    unsigned r = u + 0x7FFFu + ((u >> 16) & 1u);   // RNE
    return (unsigned short)(r >> 16);
}
__device__ __forceinline__ float bf2f(unsigned short h) {
    return __builtin_bit_cast(float, (unsigned)h << 16);
}

// WTT[j][k] (bf16, row stride 512): k<256 -> w1[j][k]; k>=256 -> (w2@w3)[j][k-256]
// bvec[j] = (w2 @ b3)[j]  (f32)
__global__ __launch_bounds__(256) void prep_weights(
        const float* __restrict__ w1, const float* __restrict__ w2,
        const float* __restrict__ w3, const float* __restrict__ b3,
        unsigned short* __restrict__ WTT, float* __restrict__ bvec) {
    const int j = blockIdx.x;    // output row of WTT
    const int k = threadIdx.x;
    __shared__ float w2row[D];
    __shared__ float red[D];
    w2row[k] = w2[j * D + k];
    __syncthreads();
    float acc = 0.f;
    #pragma unroll 8
    for (int o = 0; o < D; ++o) acc += w2row[o] * w3[o * D + k];   // coalesced in k
    WTT[(size_t)j * 512 + k]       = f2bf(w1[j * D + k]);
    WTT[(size_t)j * 512 + D + k]   = f2bf(acc);
    red[k] = w2row[k] * b3[k];
    __syncthreads();
    for (int s = 128; s > 0; s >>= 1) {
        if (k < s) red[k] += red[k + s];
        __syncthreads();
    }
    if (k == 0) bvec[j] = red[0];
}

// also zeroes cnt (runs before fill_csr on the stream) — replaces the 40us memset
__global__ __launch_bounds__(256) void convert_x(
        const float* __restrict__ x, unsigned short* __restrict__ xbf,
        int* __restrict__ cnt) {
    const size_t gid = (size_t)blockIdx.x * 256 + threadIdx.x;
    if (gid < NN) cnt[gid] = 0;
    const size_t i = gid * 8;
    if (i >= (size_t)NN * D) return;
    const float4 a = *reinterpret_cast<const float4*>(x + i);
    const float4 b = *reinterpret_cast<const float4*>(x + i + 4);
    ushort4 o0 = {f2bf(a.x), f2bf(a.y), f2bf(a.z), f2bf(a.w)};
    ushort4 o1 = {f2bf(b.x), f2bf(b.y), f2bf(b.z), f2bf(b.w)};
    *reinterpret_cast<ushort4*>(xbf + i)     = o0;
    *reinterpret_cast<ushort4*>(xbf + i + 4) = o1;
}

__global__ __launch_bounds__(256) void fill_csr(
        const int* __restrict__ ei, int* __restrict__ csr, int* __restrict__ cnt) {
    const int e = blockIdx.x * 256 + threadIdx.x;
    if (e >= NE) return;
    const int src = ei[e];
    const int dst = ei[NE + e];
    const int pos = atomicAdd(cnt + dst, 1);
    if (pos < CAP) csr[(size_t)dst * CAP + pos] = src;
}

// one wave per node: aggbf[n] = bf16( sum over in-edges of xbf[src] )
__global__ __launch_bounds__(256) void agg_gather(
        const unsigned short* __restrict__ xbf, const int* __restrict__ csr,
        const int* __restrict__ cnt, unsigned short* __restrict__ aggbf) {
    const int node = blockIdx.x * 4 + (threadIdx.x >> 6);
    const int lane = threadIdx.x & 63;
    if (node >= NN) return;
    int d = cnt[node]; if (d > CAP) d = CAP;
    const int* __restrict__ row = csr + (size_t)node * CAP;
    float a0 = 0.f, a1 = 0.f, a2 = 0.f, a3 = 0.f;
    int i = 0;
    for (; i + 2 <= d; i += 2) {
        const ushort4 v0 = *reinterpret_cast<const ushort4*>(xbf + (size_t)row[i] * D + lane * 4);
        const ushort4 v1 = *reinterpret_cast<const ushort4*>(xbf + (size_t)row[i + 1] * D + lane * 4);
        a0 += bf2f(v0.x) + bf2f(v1.x); a1 += bf2f(v0.y) + bf2f(v1.y);
        a2 += bf2f(v0.z) + bf2f(v1.z); a3 += bf2f(v0.w) + bf2f(v1.w);
    }
    if (i < d) {
        const ushort4 v = *reinterpret_cast<const ushort4*>(xbf + (size_t)row[i] * D + lane * 4);
        a0 += bf2f(v.x); a1 += bf2f(v.y); a2 += bf2f(v.z); a3 += bf2f(v.w);
    }
    ushort4 o = {f2bf(a0), f2bf(a1), f2bf(a2), f2bf(a3)};
    *reinterpret_cast<ushort4*>(aggbf + (size_t)node * D + lane * 4) = o;
}

// out[MxN] = [xbf | aggbf] (M x 512) @ WTT^T (512 x 256) + deg*bvec
// 128x128 tile, 4 waves (2x2), 16x16x32 bf16 MFMA.
// T3-minimum 2-phase pipeline: double-buffered LDS, STAGE(kt+1) issued
// before compute(kt), one vmcnt-draining __syncthreads per tile.
__global__ __launch_bounds__(256) void gemm_mfma(
        const unsigned short* __restrict__ xbf, const unsigned short* __restrict__ aggbf,
        const unsigned short* __restrict__ WTT, const float* __restrict__ bvec,
        const int* __restrict__ cnt, float* __restrict__ out) {
    __shared__ __align__(16) unsigned short ldsA[2][128 * 64];  // 2 x 16 KB
    __shared__ __align__(16) unsigned short ldsB[2][128 * 64];  // 2 x 16 KB

    const int tid  = threadIdx.x;
    const int w    = tid >> 6;
    const int lane = tid & 63;
    const int wm   = w >> 1, wn = w & 1;
    const int mb   = blockIdx.x >> 1;
    const int nb0  = (blockIdx.x & 1) * 128;
    const int gr0  = mb * 128;

    auto stage = [&](int kt, int b) {
        const unsigned short* __restrict__ srcA = (kt < 4) ? xbf : aggbf;
        const int kcA = (kt & 3) * 64;
        const int kcB = kt * 64;
        #pragma unroll
        for (int p = 0; p < 4; ++p) {
            const int idx = p * 256 + w * 64 + lane;       // 16B unit id
            const int r = idx >> 3, c = idx & 7;
            const int sw = (c ^ (r & 7)) << 3;             // pre-swizzled source col
            const unsigned short* gpA = srcA + ((size_t)(gr0 + r) << 8) + kcA + sw;
            unsigned short* lpA = &ldsA[b][(p * 256 + w * 64) << 3];   // wave-uniform
            __builtin_amdgcn_global_load_lds(
                (const __attribute__((address_space(1))) void*)(const void*)gpA,
                (__attribute__((address_space(3))) void*)(void*)lpA, 16, 0, 0);
            const unsigned short* gpB = WTT + ((size_t)(nb0 + r) << 9) + kcB + sw;
            unsigned short* lpB = &ldsB[b][(p * 256 + w * 64) << 3];
            __builtin_amdgcn_global_load_lds(
                (const __attribute__((address_space(1))) void*)(const void*)gpB,
                (__attribute__((address_space(3))) void*)(void*)lpB, 16, 0, 0);
        }
    };

    f32x4 acc[4][4];
    #pragma unroll
    for (int a = 0; a < 4; ++a)
        #pragma unroll
        for (int b = 0; b < 4; ++b) acc[a][b] = (f32x4)0.f;

    stage(0, 0);
    __syncthreads();
    #pragma unroll 2
    for (int kt = 0; kt < 8; ++kt) {
        const int cur = kt & 1;
        if (kt < 7) stage(kt + 1, cur ^ 1);      // prefetch next tile
        #pragma unroll
        for (int kh = 0; kh < 2; ++kh) {
            const int cbase = kh * 4 + (lane >> 4);            // chunk 0..7
            bf16x8 af[4], bfr[4];
            #pragma unroll
            for (int f = 0; f < 4; ++f) {
                const int ra = wm * 64 + f * 16 + (lane & 15);
                af[f] = *reinterpret_cast<const bf16x8*>(
                    &ldsA[cur][ra * 64 + ((cbase ^ (ra & 7)) << 3)]);
                const int rb = wn * 64 + f * 16 + (lane & 15);
                bfr[f] = *reinterpret_cast<const bf16x8*>(
                    &ldsB[cur][rb * 64 + ((cbase ^ (rb & 7)) << 3)]);
            }
            #pragma unroll
            for (int fm = 0; fm < 4; ++fm)
                #pragma unroll
                for (int fn = 0; fn < 4; ++fn)
                    acc[fm][fn] = __builtin_amdgcn_mfma_f32_16x16x32_bf16(
                        af[fm], bfr[fn], acc[fm][fn], 0, 0, 0);
        }
        __syncthreads();   // drains prefetch vmcnt; next tile ready
    }

    // ---- epilogue: out = acc + deg*bvec ; C/D layout col=lane&15, row=(lane>>4)*4+i
    const int col0 = nb0 + wn * 64 + (lane & 15);
    float bv[4];
    #pragma unroll
    for (int fn = 0; fn < 4; ++fn) bv[fn] = bvec[col0 + fn * 16];
    #pragma unroll
    for (int fm = 0; fm < 4; ++fm) {
        #pragma unroll
        for (int i = 0; i < 4; ++i) {
            const int row = gr0 + wm * 64 + fm * 16 + ((lane >> 4) << 2) + i;
            if (row < NN) {
                const float dg = (float)cnt[row];
                float* op = out + ((size_t)row << 8) + col0;
                #pragma unroll
                for (int fn = 0; fn < 4; ++fn)
                    op[fn * 16] = acc[fm][fn][i] + dg * bv[fn];
            }
        }
    }
}

extern "C" void kernel_launch(void* const* d_in, const int* in_sizes, int n_in,
                              void* d_out, int out_size, void* d_ws, size_t ws_size,
                              hipStream_t stream) {
    const float* x  = (const float*)d_in[0];
    const int*   ei = (const int*)d_in[1];
    const float* w1 = (const float*)d_in[2];
    const float* w2 = (const float*)d_in[3];
    const float* w3 = (const float*)d_in[4];
    const float* b3 = (const float*)d_in[5];
    float* out = (float*)d_out;

    unsigned short* xbf   = (unsigned short*)d_ws;               // NPAD*256
    unsigned short* aggbf = xbf + (size_t)NPAD * D;              // NPAD*256
    unsigned short* WTT   = aggbf + (size_t)NPAD * D;            // 256*512
    float* bvec = (float*)(WTT + (size_t)D * 512);               // 256
    int*   cnt  = (int*)(bvec + D);                              // NN
    int*   csr  = cnt + NN;                                      // NN*CAP

    prep_weights<<<D, 256, 0, stream>>>(w1, w2, w3, b3, WTT, bvec);
    convert_x<<<(NN * D) / (256 * 8), 256, 0, stream>>>(x, xbf, cnt);
    fill_csr<<<(NE + 255) / 256, 256, 0, stream>>>(ei, csr, cnt);
    agg_gather<<<(NN + 3) / 4, 256, 0, stream>>>(xbf, csr, cnt, aggbf);
    gemm_mfma<<<((NN + 127) / 128) * 2, 256, 0, stream>>>(xbf, aggbf, WTT, bvec, cnt, out);
}